// Round 13
// baseline (186.438 us; speedup 1.0000x reference)
//
#include <hip/hip_runtime.h>
#include <math.h>

typedef float f32x4 __attribute__((ext_vector_type(4)));
typedef short s16x8 __attribute__((ext_vector_type(8)));
typedef unsigned short ushort_t;

namespace {
constexpr int kH  = 8;
constexpr int kD  = 64;
constexpr int kDM = 512;
constexpr int kB  = 2;
constexpr int kS  = 2048;
constexpr size_t kNE = (size_t)kB * kS * kDM;      // 2,097,152
constexpr size_t kNL = (size_t)kB * kH * kS;       // 32,768
}  // namespace

// Truncation split: x = hi + lo + eps, |eps| <= 2^-16 |x|
__device__ __forceinline__ void split_bf16(float x, ushort_t& hi, ushort_t& lo) {
  union { float f; unsigned u; } a; a.f = x;
  hi = (ushort_t)(a.u >> 16);
  union { unsigned u; float f; } hh; hh.u = a.u & 0xffff0000u;
  union { float f; unsigned u; } r; r.f = x - hh.f;
  lo = (ushort_t)(r.u >> 16);
}
// Round-to-nearest-even bf16
__device__ __forceinline__ ushort_t rne_bf16(float x) {
  union { float f; unsigned u; } a; a.f = x;
  const unsigned t = a.u + 0x7fffu + ((a.u >> 16) & 1u);
  return (ushort_t)(t >> 16);
}
__device__ __forceinline__ float bf_to_f(unsigned u16) {
  union { unsigned u; float f; } a; a.u = u16 << 16; return a.f;
}

// ---------------------------------------------------------------------------
// Kernel 1: K/V projection via MFMA; Wk/Wv split in-register from fp32.
// z==2 blocks instead split Wo (permuted) and Wq for the later kernels.
// grid (B*S/64, H, 3): z=0 -> k_hi [b,h,s,d]; z=1 -> vt_hi [b,h,d,key];
// z=2 -> weight prep (blocks 0..127: Wo; block 128: Wq; rest idle).
// ---------------------------------------------------------------------------
__global__ __launch_bounds__(256, 4)
void kv_proj_kernel(const float* __restrict__ xk, const float* __restrict__ xv,
                    const float* __restrict__ Wk, const float* __restrict__ bk,
                    const float* __restrict__ Wv, const float* __restrict__ bv,
                    const float* __restrict__ Wo, const float* __restrict__ Wq,
                    ushort_t* __restrict__ wo_h, ushort_t* __restrict__ wo_l,
                    ushort_t* __restrict__ wq_h, ushort_t* __restrict__ wq_l,
                    ushort_t* __restrict__ k_hi, ushort_t* __restrict__ vt_hi) {
  const int which = blockIdx.z;
  if (which == 2) {
    const int bid = blockIdx.y * 64 + blockIdx.x;
    if (bid < 128) {
      // Wo permuted split: woP[e][g] = Wo[e][(g&63)*8 + (g>>6)]
      const int gi = (bid * 256 + threadIdx.x) * 8;
      const int e  = gi >> 9;
      const int g0 = gi & 511;
      const int fbase = (g0 & 63) * 8 + (g0 >> 6);
      ushort_t h8[8], l8[8];
      #pragma unroll
      for (int j = 0; j < 8; ++j)
        split_bf16(Wo[(size_t)e * kDM + fbase + j * 8], h8[j], l8[j]);
      int4 hp, lp;
      hp.x = (int)((unsigned)h8[0] | ((unsigned)h8[1] << 16));
      hp.y = (int)((unsigned)h8[2] | ((unsigned)h8[3] << 16));
      hp.z = (int)((unsigned)h8[4] | ((unsigned)h8[5] << 16));
      hp.w = (int)((unsigned)h8[6] | ((unsigned)h8[7] << 16));
      lp.x = (int)((unsigned)l8[0] | ((unsigned)l8[1] << 16));
      lp.y = (int)((unsigned)l8[2] | ((unsigned)l8[3] << 16));
      lp.z = (int)((unsigned)l8[4] | ((unsigned)l8[5] << 16));
      lp.w = (int)((unsigned)l8[6] | ((unsigned)l8[7] << 16));
      *(int4*)&wo_h[(size_t)e * kDM + g0] = hp;
      *(int4*)&wo_l[(size_t)e * kDM + g0] = lp;
    } else if (bid == 128) {
      #pragma unroll
      for (int cc = 0; cc < 4; ++cc) {
        const int i = (cc * 256 + threadIdx.x) * 4;
        const float4 v = *(const float4*)&Wq[i];
        ushort_t h4[4], l4[4];
        split_bf16(v.x, h4[0], l4[0]);
        split_bf16(v.y, h4[1], l4[1]);
        split_bf16(v.z, h4[2], l4[2]);
        split_bf16(v.w, h4[3], l4[3]);
        int2 hp, lp;
        hp.x = (int)((unsigned)h4[0] | ((unsigned)h4[1] << 16));
        hp.y = (int)((unsigned)h4[2] | ((unsigned)h4[3] << 16));
        lp.x = (int)((unsigned)l4[0] | ((unsigned)l4[1] << 16));
        lp.y = (int)((unsigned)l4[2] | ((unsigned)l4[3] << 16));
        *(int2*)&wq_h[i] = hp;
        *(int2*)&wq_l[i] = lp;
      }
    }
    return;
  }

  __shared__ __align__(16) ushort_t Xh[64][72];
  __shared__ __align__(16) ushort_t Xl[64][72];
  const float* x = which ? xv : xk;
  const float* W = which ? Wv : Wk;
  const float* bias = which ? bv : bk;
  const int h = blockIdx.y;
  const int t0g = blockIdx.x * 64;
  const int b = t0g >> 11, s0 = t0g & (kS - 1);
  const int tid  = threadIdx.x;
  const int w    = tid >> 6;
  const int lane = tid & 63;
  const int ln   = lane & 15;
  const int quad = lane >> 4;
  const size_t hb = ((size_t)b * kH + h) * (size_t)(kS * kD);

  #pragma unroll
  for (int cc = 0; cc < 4; ++cc) {
    const int id = tid + cc * 256;
    const int r = id >> 4, c = id & 15;
    const float4 v = *(const float4*)&x[((size_t)t0g + r) * kDM + h * kD + c * 4];
    ushort_t hh[4], ll[4];
    split_bf16(v.x, hh[0], ll[0]);
    split_bf16(v.y, hh[1], ll[1]);
    split_bf16(v.z, hh[2], ll[2]);
    split_bf16(v.w, hh[3], ll[3]);
    int2 hp, lp;
    hp.x = (int)((unsigned)hh[0] | ((unsigned)hh[1] << 16));
    hp.y = (int)((unsigned)hh[2] | ((unsigned)hh[3] << 16));
    lp.x = (int)((unsigned)ll[0] | ((unsigned)ll[1] << 16));
    lp.y = (int)((unsigned)ll[2] | ((unsigned)ll[3] << 16));
    *(int2*)&Xh[r][c * 4] = hp;
    *(int2*)&Xl[r][c * 4] = lp;
  }
  __syncthreads();

  f32x4 C[4];
  #pragma unroll
  for (int eb = 0; eb < 4; ++eb) C[eb] = (f32x4){0.f, 0.f, 0.f, 0.f};
  #pragma unroll
  for (int kc = 0; kc < 2; ++kc) {
    const s16x8 ah = *(const s16x8*)&Xh[w * 16 + ln][kc * 32 + quad * 8];
    const s16x8 al = *(const s16x8*)&Xl[w * 16 + ln][kc * 32 + quad * 8];
    #pragma unroll
    for (int eb = 0; eb < 4; ++eb) {
      const float* wp = &W[(size_t)(eb * 16 + ln) * kD + kc * 32 + quad * 8];
      const float4 w0 = *(const float4*)wp;
      const float4 w1 = *(const float4*)(wp + 4);
      const float ws[8] = {w0.x, w0.y, w0.z, w0.w, w1.x, w1.y, w1.z, w1.w};
      s16x8 bh, bl;
      #pragma unroll
      for (int j = 0; j < 8; ++j) {
        ushort_t hi, lo;
        split_bf16(ws[j], hi, lo);
        bh[j] = (short)hi; bl[j] = (short)lo;
      }
      C[eb] = __builtin_amdgcn_mfma_f32_16x16x32_bf16(ah, bh, C[eb], 0, 0, 0);
      C[eb] = __builtin_amdgcn_mfma_f32_16x16x32_bf16(ah, bl, C[eb], 0, 0, 0);
      C[eb] = __builtin_amdgcn_mfma_f32_16x16x32_bf16(al, bh, C[eb], 0, 0, 0);
    }
  }
  __syncthreads();

  if (which == 0) {
    #pragma unroll
    for (int eb = 0; eb < 4; ++eb) {
      const float be = bias[eb * 16 + ln];
      #pragma unroll
      for (int r = 0; r < 4; ++r)
        Xh[w * 16 + quad * 4 + r][eb * 16 + ln] = rne_bf16(C[eb][r] + be);
    }
    __syncthreads();
    #pragma unroll
    for (int cc = 0; cc < 2; ++cc) {
      const int id = tid + cc * 256;
      const int r = id >> 3, c = id & 7;
      *(int4*)&k_hi[hb + (size_t)(s0 + r) * kD + c * 8] = *(int4*)&Xh[r][c * 8];
    }
  } else {
    #pragma unroll
    for (int eb = 0; eb < 4; ++eb) {
      const float be = bias[eb * 16 + ln];
      #pragma unroll
      for (int r = 0; r < 4; ++r)
        Xh[eb * 16 + ln][w * 16 + quad * 4 + r] = rne_bf16(C[eb][r] + be);
    }
    __syncthreads();
    #pragma unroll
    for (int cc = 0; cc < 2; ++cc) {
      const int id = tid + cc * 256;
      const int r = id >> 3, c = id & 7;
      *(int4*)&vt_hi[hb + (size_t)r * kS + s0 + c * 8] = *(int4*)&Xh[r][c * 8];
    }
  }
}

// ---------------------------------------------------------------------------
// Kernel 2: MFMA flash attention = R10 structure (4 waves, 32 q-rows/wave,
// splitK x4, 4 blocks/CU) + REGISTER-PREFETCH pipeline: tile kt+1's global
// K/V loads are issued right after barrier-2 so their latency overlaps tile
// kt's compute; the LDS writes happen at the next iteration's barrier point.
// Same LDS / barriers / memory traffic as R10; only load latency moves off
// the critical path. VGPR ~84 (cap 128 via launch_bounds(256,4); R12's
// 8-wave variant spilled at 32 VGPR -> +38MB scratch writes).
// ---------------------------------------------------------------------------
__global__ __launch_bounds__(256, 4)
void attn_kernel(const float* __restrict__ xq,
                 const ushort_t* __restrict__ wq_h, const ushort_t* __restrict__ wq_l,
                 const float* __restrict__ bq,
                 const ushort_t* __restrict__ k_hi, const ushort_t* __restrict__ vt_hi,
                 const int* __restrict__ mask,
                 ushort_t* __restrict__ Opart, float* __restrict__ lws) {
  // smem region (18432 B) is QT[128][72] in preamble/epilogue, Kh|Vh in loop.
  __shared__ __align__(16) ushort_t smem[128 * 72];
  __shared__ __align__(16) ushort_t Pbm[4 * 32 * 40];   // per-wave P (32q x 32k)
  __shared__ float Mz[64];
  ushort_t (*QT)[72] = (ushort_t(*)[72])smem;
  ushort_t (*Kh)[72] = (ushort_t(*)[72])smem;              // [key][d]
  ushort_t (*Vh)[72] = (ushort_t(*)[72])(smem + 64 * 72);  // [d][key]
  ushort_t (*Pb)[32][40] = (ushort_t(*)[32][40])Pbm;

  const int tid  = threadIdx.x;
  const int w    = tid >> 6;          // wave 0..3
  const int lane = tid & 63;
  const int ln   = lane & 15;
  const int quad = lane >> 4;
  const int h    = blockIdx.y;
  const int b    = blockIdx.z >> 2;
  const int quarter = blockIdx.z & 3;
  const int q0   = blockIdx.x * 128;
  const size_t hb = ((size_t)b * kH + h) * (size_t)(kS * kD);

  // staging geometry (fixed per thread)
  const int sr = tid >> 3;            // row 0..31 (+32 on second chunk)
  const int sc = (tid & 7) * 8;       // 16B column offset

  // ---- fused Q projection: 32 rows/wave, RNE bf16, LDS transpose ----
  s16x8 aqh[2][2];   // [group][db]
  #pragma unroll
  for (int g = 0; g < 2; ++g) {
    const int qrow = q0 + w * 32 + g * 16 + ln;
    f32x4 C[4];
    #pragma unroll
    for (int eb = 0; eb < 4; ++eb) C[eb] = (f32x4){0.f, 0.f, 0.f, 0.f};
    #pragma unroll
    for (int kc = 0; kc < 2; ++kc) {
      const float* xp = &xq[((size_t)b * kS + qrow) * kDM + h * kD + kc * 32 + quad * 8];
      const float4 x0 = *(const float4*)xp;
      const float4 x1 = *(const float4*)(xp + 4);
      const float xs[8] = {x0.x, x0.y, x0.z, x0.w, x1.x, x1.y, x1.z, x1.w};
      s16x8 ah, al;
      #pragma unroll
      for (int j = 0; j < 8; ++j) {
        ushort_t hi, lo;
        split_bf16(xs[j], hi, lo);
        ah[j] = (short)hi; al[j] = (short)lo;
      }
      #pragma unroll
      for (int eb = 0; eb < 4; ++eb) {
        const s16x8 bh = *(const s16x8*)&wq_h[(size_t)(eb * 16 + ln) * kD + kc * 32 + quad * 8];
        const s16x8 bl = *(const s16x8*)&wq_l[(size_t)(eb * 16 + ln) * kD + kc * 32 + quad * 8];
        C[eb] = __builtin_amdgcn_mfma_f32_16x16x32_bf16(ah, bh, C[eb], 0, 0, 0);
        C[eb] = __builtin_amdgcn_mfma_f32_16x16x32_bf16(ah, bl, C[eb], 0, 0, 0);
        C[eb] = __builtin_amdgcn_mfma_f32_16x16x32_bf16(al, bh, C[eb], 0, 0, 0);
      }
    }
    #pragma unroll
    for (int eb = 0; eb < 4; ++eb) {
      const float be = bq[eb * 16 + ln];
      #pragma unroll
      for (int r = 0; r < 4; ++r)
        QT[w * 32 + g * 16 + quad * 4 + r][eb * 16 + ln] = rne_bf16(C[eb][r] + be);
    }
    // same-wave readback (wave-private rows; compiler inserts lgkmcnt)
    #pragma unroll
    for (int db = 0; db < 2; ++db)
      aqh[g][db] = *(const s16x8*)&QT[w * 32 + g * 16 + ln][db * 32 + quad * 8];
  }

  f32x4 O[2][4];
  #pragma unroll
  for (int g = 0; g < 2; ++g)
    #pragma unroll
    for (int db = 0; db < 4; ++db) O[g][db] = (f32x4){0.f, 0.f, 0.f, 0.f};
  float rs[2][4] = {};

  // ---- prologue: prefetch tile kt0 into registers ----
  const int kt0 = quarter * 8;
  int4 kr[2], vr[2];
  int mload = 0;
  {
    const ushort_t* gkh = k_hi + hb + (size_t)kt0 * 64 * kD;
    const ushort_t* gvh = vt_hi + hb + (size_t)kt0 * 64;
    #pragma unroll
    for (int cc = 0; cc < 2; ++cc) {
      const int r = sr + cc * 32;
      kr[cc] = *(const int4*)&gkh[r * kD + sc];
      vr[cc] = *(const int4*)&gvh[(size_t)r * kS + sc];
    }
    if (tid < 64) mload = mask[(size_t)b * kS + kt0 * 64 + tid];
  }

  // ---- k-loop: this quarter's 8 tiles of 64 keys, register-prefetched ----
  for (int i = 0; i < 8; ++i) {
    __syncthreads();   // all waves done reading Kh/Vh (or QT) from prev phase
    #pragma unroll
    for (int cc = 0; cc < 2; ++cc) {
      const int r = sr + cc * 32;
      *(int4*)&Kh[r][sc] = kr[cc];
      *(int4*)&Vh[r][sc] = vr[cc];
    }
    if (tid < 64) Mz[tid] = (mload != 0) ? 1.0f : 0.0f;
    __syncthreads();

    // issue NEXT tile's global loads now; latency overlaps this tile's compute
    if (i < 7) {
      const int ktn = kt0 + i + 1;
      const ushort_t* gkh = k_hi + hb + (size_t)ktn * 64 * kD;
      const ushort_t* gvh = vt_hi + hb + (size_t)ktn * 64;
      #pragma unroll
      for (int cc = 0; cc < 2; ++cc) {
        const int r = sr + cc * 32;
        kr[cc] = *(const int4*)&gkh[r * kD + sc];
        vr[cc] = *(const int4*)&gvh[(size_t)r * kS + sc];
      }
      if (tid < 64) mload = mask[(size_t)b * kS + ktn * 64 + tid];
    }

    #pragma unroll
    for (int h32 = 0; h32 < 2; ++h32) {
      // S = Q K^T for 32 keys x 32 q-rows (1-term)
      f32x4 C[2][2];
      #pragma unroll
      for (int g = 0; g < 2; ++g) {
        C[g][0] = (f32x4){0.f, 0.f, 0.f, 0.f};
        C[g][1] = (f32x4){0.f, 0.f, 0.f, 0.f};
      }
      #pragma unroll
      for (int db = 0; db < 2; ++db) {
        const s16x8 bh0 = *(const s16x8*)&Kh[h32 * 32 + ln][db * 32 + quad * 8];
        const s16x8 bh1 = *(const s16x8*)&Kh[h32 * 32 + 16 + ln][db * 32 + quad * 8];
        #pragma unroll
        for (int g = 0; g < 2; ++g) {
          C[g][0] = __builtin_amdgcn_mfma_f32_16x16x32_bf16(aqh[g][db], bh0, C[g][0], 0, 0, 0);
          C[g][1] = __builtin_amdgcn_mfma_f32_16x16x32_bf16(aqh[g][db], bh1, C[g][1], 0, 0, 0);
        }
      }
      // p = mask*exp(0.25 s) -> RNE bf16; l sums the SAME rounded p
      #pragma unroll
      for (int g = 0; g < 2; ++g) {
        #pragma unroll
        for (int kb = 0; kb < 2; ++kb) {
          const float mz = Mz[h32 * 32 + kb * 16 + ln];
          #pragma unroll
          for (int r = 0; r < 4; ++r) {
            const float p = mz * __expf(0.25f * C[g][kb][r]);
            union { float f; unsigned u; } pa; pa.f = p;
            const unsigned t = pa.u + 0x7fffu + ((pa.u >> 16) & 1u);
            Pb[w][g * 16 + quad * 4 + r][kb * 16 + ln] = (ushort_t)(t >> 16);
            union { unsigned u; float f; } pr; pr.u = t & 0xffff0000u;
            rs[g][r] += pr.f;
          }
        }
      }
      // O += P V; V-frags shared across both q-groups
      {
        const s16x8 ph0 = *(const s16x8*)&Pb[w][ln][quad * 8];
        const s16x8 ph1 = *(const s16x8*)&Pb[w][16 + ln][quad * 8];
        #pragma unroll
        for (int db = 0; db < 4; ++db) {
          const s16x8 vh = *(const s16x8*)&Vh[db * 16 + ln][h32 * 32 + quad * 8];
          O[0][db] = __builtin_amdgcn_mfma_f32_16x16x32_bf16(ph0, vh, O[0][db], 0, 0, 0);
          O[1][db] = __builtin_amdgcn_mfma_f32_16x16x32_bf16(ph1, vh, O[1][db], 0, 0, 0);
        }
      }
    }
  }

  // ---- l partials: 16-lane group reduce, plain store ----
  #pragma unroll
  for (int m = 1; m < 16; m <<= 1) {
    #pragma unroll
    for (int g = 0; g < 2; ++g)
      #pragma unroll
      for (int r = 0; r < 4; ++r) rs[g][r] += __shfl_xor(rs[g][r], m);
  }
  if (ln == 0) {
    #pragma unroll
    for (int g = 0; g < 2; ++g) {
      float* lp = lws + (size_t)quarter * kNL + ((size_t)b * kH + h) * kS +
                  q0 + w * 32 + g * 16 + quad * 4;
      #pragma unroll
      for (int r = 0; r < 4; ++r) lp[r] = rs[g][r];
    }
  }

  // ---- O partials: RNE bf16, LDS repack, coalesced stores ----
  __syncthreads();   // Kh/Vh dead
  #pragma unroll
  for (int g = 0; g < 2; ++g)
    #pragma unroll
    for (int db = 0; db < 4; ++db)
      #pragma unroll
      for (int r = 0; r < 4; ++r)
        QT[w * 32 + g * 16 + quad * 4 + r][db * 16 + ln] = rne_bf16(O[g][db][r]);
  __syncthreads();
  ushort_t* op = Opart + (size_t)quarter * kNE;
  #pragma unroll
  for (int cc = 0; cc < 4; ++cc) {
    const int id = tid + cc * 256;
    const int r = id >> 3, c = id & 7;
    *(int4*)&op[((size_t)b * kS + q0 + r) * kDM + h * kD + c * 8] = *(int4*)&QT[r][c * 8];
  }
}

// ---------------------------------------------------------------------------
// Kernel 3: MFMA output projection with fused split-K combine (R10 shape).
// t-tile 32, e-tile 128, k-step 32 -> Opart re-read factor 4.
// grid (B*S/32, DM/128), block 256 (4 waves: tsub = w&1, esub = w>>1).
// ---------------------------------------------------------------------------
__global__ __launch_bounds__(256, 2)
void out_proj_kernel(const ushort_t* __restrict__ Opart, const float* __restrict__ lws,
                     const ushort_t* __restrict__ wh, const ushort_t* __restrict__ wl,
                     const float* __restrict__ bo, float* __restrict__ out) {
  __shared__ __align__(16) ushort_t Ah[32][40];
  __shared__ __align__(16) ushort_t Al[32][40];
  __shared__ __align__(16) ushort_t Bh[128][40];
  __shared__ __align__(16) ushort_t Bl[128][40];
  __shared__ float linv[kH][32];
  const int t0 = blockIdx.x * 32;
  const int e0 = blockIdx.y * 128;
  const int b  = t0 >> 11;
  const int s0 = t0 & (kS - 1);
  const int tid  = threadIdx.x;
  const int w    = tid >> 6;
  const int lane = tid & 63;
  const int ln   = lane & 15;
  const int quad = lane >> 4;
  const int tsub = w & 1;
  const int esub = w >> 1;

  {  // 8 heads x 32 rows: one l-sum per thread
    const int hh = tid >> 5, r = tid & 31;
    const size_t base = ((size_t)b * kH + hh) * kS + s0 + r;
    linv[hh][r] = 1.0f / (lws[base] + lws[kNL + base] +
                          lws[2 * kNL + base] + lws[3 * kNL + base]);
  }

  f32x4 C[4];
  #pragma unroll
  for (int eb = 0; eb < 4; ++eb) C[eb] = (f32x4){0.f, 0.f, 0.f, 0.f};

  for (int k0 = 0; k0 < kDM; k0 += 32) {
    __syncthreads();
    const int hh = k0 >> 6;
    // A: 32 rows x 32 cols; sum 4 bf16 partials -> /l -> split (1 chunk/thread)
    {
      const int r = tid >> 3, c4 = (tid & 7) * 4;
      const size_t off = (size_t)(t0 + r) * kDM + k0 + c4;
      float a0 = 0.f, a1 = 0.f, a2 = 0.f, a3 = 0.f;
      #pragma unroll
      for (int q = 0; q < 4; ++q) {
        const int2 u = *(const int2*)&Opart[(size_t)q * kNE + off];
        a0 += bf_to_f((unsigned)u.x & 0xffffu);
        a1 += bf_to_f((unsigned)u.x >> 16);
        a2 += bf_to_f((unsigned)u.y & 0xffffu);
        a3 += bf_to_f((unsigned)u.y >> 16);
      }
      const float li = linv[hh][r];
      a0 *= li; a1 *= li; a2 *= li; a3 *= li;
      ushort_t h4[4], l4[4];
      split_bf16(a0, h4[0], l4[0]);
      split_bf16(a1, h4[1], l4[1]);
      split_bf16(a2, h4[2], l4[2]);
      split_bf16(a3, h4[3], l4[3]);
      int2 hp, lp;
      hp.x = (int)((unsigned)h4[0] | ((unsigned)h4[1] << 16));
      hp.y = (int)((unsigned)h4[2] | ((unsigned)h4[3] << 16));
      lp.x = (int)((unsigned)l4[0] | ((unsigned)l4[1] << 16));
      lp.y = (int)((unsigned)l4[2] | ((unsigned)l4[3] << 16));
      *(int2*)&Ah[r][c4] = hp;
      *(int2*)&Al[r][c4] = lp;
    }
    // B: 128 rows x 32 cols from pre-split permuted Wo (2 chunks/thread)
    #pragma unroll
    for (int cc = 0; cc < 2; ++cc) {
      const int id = tid + cc * 256;
      const int r = id >> 2, c = (id & 3) * 8;
      *(int4*)&Bh[r][c] = *(const int4*)&wh[(size_t)(e0 + r) * kDM + k0 + c];
      *(int4*)&Bl[r][c] = *(const int4*)&wl[(size_t)(e0 + r) * kDM + k0 + c];
    }
    __syncthreads();
    const s16x8 ah = *(const s16x8*)&Ah[tsub * 16 + ln][quad * 8];
    const s16x8 al = *(const s16x8*)&Al[tsub * 16 + ln][quad * 8];
    #pragma unroll
    for (int eb = 0; eb < 4; ++eb) {
      const s16x8 bh = *(const s16x8*)&Bh[esub * 64 + eb * 16 + ln][quad * 8];
      const s16x8 bl = *(const s16x8*)&Bl[esub * 64 + eb * 16 + ln][quad * 8];
      C[eb] = __builtin_amdgcn_mfma_f32_16x16x32_bf16(ah, bh, C[eb], 0, 0, 0);
      C[eb] = __builtin_amdgcn_mfma_f32_16x16x32_bf16(ah, bl, C[eb], 0, 0, 0);
      C[eb] = __builtin_amdgcn_mfma_f32_16x16x32_bf16(al, bh, C[eb], 0, 0, 0);
    }
  }

  #pragma unroll
  for (int eb = 0; eb < 4; ++eb) {
    const int e = e0 + esub * 64 + eb * 16 + ln;
    const float be = bo[e];
    #pragma unroll
    for (int r = 0; r < 4; ++r) {
      const int t = t0 + tsub * 16 + quad * 4 + r;
      out[(size_t)t * kDM + e] = C[eb][r] + be;
    }
  }
}

// ---------------------------------------------------------------------------
extern "C" void kernel_launch(void* const* d_in, const int* in_sizes, int n_in,
                              void* d_out, int out_size, void* d_ws, size_t ws_size,
                              hipStream_t stream) {
  const float* query = (const float*)d_in[0];
  const float* key   = (const float*)d_in[1];
  const float* value = (const float*)d_in[2];
  const float* Wq = (const float*)d_in[3];
  const float* bq = (const float*)d_in[4];
  const float* Wk = (const float*)d_in[5];
  const float* bk = (const float*)d_in[6];
  const float* Wv = (const float*)d_in[7];
  const float* bv = (const float*)d_in[8];
  const float* Wo = (const float*)d_in[9];
  const float* bo = (const float*)d_in[10];
  const int* mask = (const int*)d_in[11];
  float* out = (float*)d_out;

  ushort_t* k_hi  = (ushort_t*)d_ws;            // 4MB
  ushort_t* vt_hi = k_hi + kNE;                 // 4MB
  ushort_t* wo_h  = vt_hi + kNE;                // 512KB
  ushort_t* wo_l  = wo_h + (size_t)kDM * kDM;   // 512KB
  ushort_t* Opart = wo_l + (size_t)kDM * kDM;   // 16MB (4 quarters, bf16)
  float*    lws   = (float*)(Opart + 4 * kNE);  // 512KB (4 quarters)
  ushort_t* wq_h  = (ushort_t*)(lws + 4 * kNL); // 2 x 8KB
  ushort_t* wq_l  = wq_h + kD * kD;             // total ~25.5 MB

  kv_proj_kernel<<<dim3(kB * kS / 64, kH, 3), 256, 0, stream>>>(
      key, value, Wk, bk, Wv, bv, Wo, Wq, wo_h, wo_l, wq_h, wq_l, k_hi, vt_hi);
  attn_kernel<<<dim3(kS / 128, kH, kB * 4), 256, 0, stream>>>(
      query, wq_h, wq_l, bq, k_hi, vt_hi, mask, Opart, lws);
  out_proj_kernel<<<dim3(kB * kS / 32, kDM / 128), 256, 0, stream>>>(
      Opart, lws, wo_h, wo_l, bo, out);
}

// Round 14
// 170.703 us; speedup vs baseline: 1.0922x; 1.0922x over previous
//
#include <hip/hip_runtime.h>
#include <math.h>

typedef float f32x4 __attribute__((ext_vector_type(4)));
typedef short s16x8 __attribute__((ext_vector_type(8)));
typedef unsigned short ushort_t;

namespace {
constexpr int kH  = 8;
constexpr int kD  = 64;
constexpr int kDM = 512;
constexpr int kB  = 2;
constexpr int kS  = 2048;
constexpr size_t kNE = (size_t)kB * kS * kDM;      // 2,097,152
constexpr size_t kNL = (size_t)kB * kH * kS;       // 32,768
}  // namespace

// Truncation split: x = hi + lo + eps, |eps| <= 2^-16 |x|
__device__ __forceinline__ void split_bf16(float x, ushort_t& hi, ushort_t& lo) {
  union { float f; unsigned u; } a; a.f = x;
  hi = (ushort_t)(a.u >> 16);
  union { unsigned u; float f; } hh; hh.u = a.u & 0xffff0000u;
  union { float f; unsigned u; } r; r.f = x - hh.f;
  lo = (ushort_t)(r.u >> 16);
}
// Round-to-nearest-even bf16
__device__ __forceinline__ ushort_t rne_bf16(float x) {
  union { float f; unsigned u; } a; a.f = x;
  const unsigned t = a.u + 0x7fffu + ((a.u >> 16) & 1u);
  return (ushort_t)(t >> 16);
}
__device__ __forceinline__ float bf_to_f(unsigned u16) {
  union { unsigned u; float f; } a; a.u = u16 << 16; return a.f;
}

// ---------------------------------------------------------------------------
// Kernel 1: K/V projection via MFMA; Wk/Wv split in-register from fp32.
// z==2 blocks instead split Wo (permuted) and Wq for the later kernels.
// grid (B*S/64, H, 3): z=0 -> k_hi [b,h,s,d]; z=1 -> vt_hi [b,h,d,key];
// z=2 -> weight prep (blocks 0..127: Wo; block 128: Wq; rest idle).
// ---------------------------------------------------------------------------
__global__ __launch_bounds__(256, 2)
void kv_proj_kernel(const float* __restrict__ xk, const float* __restrict__ xv,
                    const float* __restrict__ Wk, const float* __restrict__ bk,
                    const float* __restrict__ Wv, const float* __restrict__ bv,
                    const float* __restrict__ Wo, const float* __restrict__ Wq,
                    ushort_t* __restrict__ wo_h, ushort_t* __restrict__ wo_l,
                    ushort_t* __restrict__ wq_h, ushort_t* __restrict__ wq_l,
                    ushort_t* __restrict__ k_hi, ushort_t* __restrict__ vt_hi) {
  const int which = blockIdx.z;
  if (which == 2) {
    const int bid = blockIdx.y * 64 + blockIdx.x;
    if (bid < 128) {
      // Wo permuted split: woP[e][g] = Wo[e][(g&63)*8 + (g>>6)]
      const int gi = (bid * 256 + threadIdx.x) * 8;
      const int e  = gi >> 9;
      const int g0 = gi & 511;
      const int fbase = (g0 & 63) * 8 + (g0 >> 6);
      ushort_t h8[8], l8[8];
      #pragma unroll
      for (int j = 0; j < 8; ++j)
        split_bf16(Wo[(size_t)e * kDM + fbase + j * 8], h8[j], l8[j]);
      int4 hp, lp;
      hp.x = (int)((unsigned)h8[0] | ((unsigned)h8[1] << 16));
      hp.y = (int)((unsigned)h8[2] | ((unsigned)h8[3] << 16));
      hp.z = (int)((unsigned)h8[4] | ((unsigned)h8[5] << 16));
      hp.w = (int)((unsigned)h8[6] | ((unsigned)h8[7] << 16));
      lp.x = (int)((unsigned)l8[0] | ((unsigned)l8[1] << 16));
      lp.y = (int)((unsigned)l8[2] | ((unsigned)l8[3] << 16));
      lp.z = (int)((unsigned)l8[4] | ((unsigned)l8[5] << 16));
      lp.w = (int)((unsigned)l8[6] | ((unsigned)l8[7] << 16));
      *(int4*)&wo_h[(size_t)e * kDM + g0] = hp;
      *(int4*)&wo_l[(size_t)e * kDM + g0] = lp;
    } else if (bid == 128) {
      #pragma unroll
      for (int cc = 0; cc < 4; ++cc) {
        const int i = (cc * 256 + threadIdx.x) * 4;
        const float4 v = *(const float4*)&Wq[i];
        ushort_t h4[4], l4[4];
        split_bf16(v.x, h4[0], l4[0]);
        split_bf16(v.y, h4[1], l4[1]);
        split_bf16(v.z, h4[2], l4[2]);
        split_bf16(v.w, h4[3], l4[3]);
        int2 hp, lp;
        hp.x = (int)((unsigned)h4[0] | ((unsigned)h4[1] << 16));
        hp.y = (int)((unsigned)h4[2] | ((unsigned)h4[3] << 16));
        lp.x = (int)((unsigned)l4[0] | ((unsigned)l4[1] << 16));
        lp.y = (int)((unsigned)l4[2] | ((unsigned)l4[3] << 16));
        *(int2*)&wq_h[i] = hp;
        *(int2*)&wq_l[i] = lp;
      }
    }
    return;
  }

  __shared__ __align__(16) ushort_t Xh[64][72];
  __shared__ __align__(16) ushort_t Xl[64][72];
  const float* x = which ? xv : xk;
  const float* W = which ? Wv : Wk;
  const float* bias = which ? bv : bk;
  const int h = blockIdx.y;
  const int t0g = blockIdx.x * 64;
  const int b = t0g >> 11, s0 = t0g & (kS - 1);
  const int tid  = threadIdx.x;
  const int w    = tid >> 6;
  const int lane = tid & 63;
  const int ln   = lane & 15;
  const int quad = lane >> 4;
  const size_t hb = ((size_t)b * kH + h) * (size_t)(kS * kD);

  #pragma unroll
  for (int cc = 0; cc < 4; ++cc) {
    const int id = tid + cc * 256;
    const int r = id >> 4, c = id & 15;
    const float4 v = *(const float4*)&x[((size_t)t0g + r) * kDM + h * kD + c * 4];
    ushort_t hh[4], ll[4];
    split_bf16(v.x, hh[0], ll[0]);
    split_bf16(v.y, hh[1], ll[1]);
    split_bf16(v.z, hh[2], ll[2]);
    split_bf16(v.w, hh[3], ll[3]);
    int2 hp, lp;
    hp.x = (int)((unsigned)hh[0] | ((unsigned)hh[1] << 16));
    hp.y = (int)((unsigned)hh[2] | ((unsigned)hh[3] << 16));
    lp.x = (int)((unsigned)ll[0] | ((unsigned)ll[1] << 16));
    lp.y = (int)((unsigned)ll[2] | ((unsigned)ll[3] << 16));
    *(int2*)&Xh[r][c * 4] = hp;
    *(int2*)&Xl[r][c * 4] = lp;
  }
  __syncthreads();

  f32x4 C[4];
  #pragma unroll
  for (int eb = 0; eb < 4; ++eb) C[eb] = (f32x4){0.f, 0.f, 0.f, 0.f};
  #pragma unroll
  for (int kc = 0; kc < 2; ++kc) {
    const s16x8 ah = *(const s16x8*)&Xh[w * 16 + ln][kc * 32 + quad * 8];
    const s16x8 al = *(const s16x8*)&Xl[w * 16 + ln][kc * 32 + quad * 8];
    #pragma unroll
    for (int eb = 0; eb < 4; ++eb) {
      const float* wp = &W[(size_t)(eb * 16 + ln) * kD + kc * 32 + quad * 8];
      const float4 w0 = *(const float4*)wp;
      const float4 w1 = *(const float4*)(wp + 4);
      const float ws[8] = {w0.x, w0.y, w0.z, w0.w, w1.x, w1.y, w1.z, w1.w};
      s16x8 bh, bl;
      #pragma unroll
      for (int j = 0; j < 8; ++j) {
        ushort_t hi, lo;
        split_bf16(ws[j], hi, lo);
        bh[j] = (short)hi; bl[j] = (short)lo;
      }
      C[eb] = __builtin_amdgcn_mfma_f32_16x16x32_bf16(ah, bh, C[eb], 0, 0, 0);
      C[eb] = __builtin_amdgcn_mfma_f32_16x16x32_bf16(ah, bl, C[eb], 0, 0, 0);
      C[eb] = __builtin_amdgcn_mfma_f32_16x16x32_bf16(al, bh, C[eb], 0, 0, 0);
    }
  }
  __syncthreads();

  if (which == 0) {
    #pragma unroll
    for (int eb = 0; eb < 4; ++eb) {
      const float be = bias[eb * 16 + ln];
      #pragma unroll
      for (int r = 0; r < 4; ++r)
        Xh[w * 16 + quad * 4 + r][eb * 16 + ln] = rne_bf16(C[eb][r] + be);
    }
    __syncthreads();
    #pragma unroll
    for (int cc = 0; cc < 2; ++cc) {
      const int id = tid + cc * 256;
      const int r = id >> 3, c = id & 7;
      *(int4*)&k_hi[hb + (size_t)(s0 + r) * kD + c * 8] = *(int4*)&Xh[r][c * 8];
    }
  } else {
    #pragma unroll
    for (int eb = 0; eb < 4; ++eb) {
      const float be = bias[eb * 16 + ln];
      #pragma unroll
      for (int r = 0; r < 4; ++r)
        Xh[eb * 16 + ln][w * 16 + quad * 4 + r] = rne_bf16(C[eb][r] + be);
    }
    __syncthreads();
    #pragma unroll
    for (int cc = 0; cc < 2; ++cc) {
      const int id = tid + cc * 256;
      const int r = id >> 3, c = id & 7;
      *(int4*)&vt_hi[hb + (size_t)r * kS + s0 + c * 8] = *(int4*)&Xh[r][c * 8];
    }
  }
}

// ---------------------------------------------------------------------------
// Kernel 2: MFMA flash attention (R10 body — best measured) + XCD-aware
// block swizzle. 1-D grid of 1024; decode id = r + 8*(x + 16*gtop) so the
// 16 q-blocks sharing one (h,b,quarter) K/V slice (128 KB) all have the
// same id%8 -> same XCD -> K/V stays resident in that XCD's L2 (8 groups
// x 128 KB = 1 MB per XCD). Pure index remap, no structural change.
// Block 256 (4 waves), q-tile 128, wave owns 32 q-rows, split-K x4.
// Max-free softmax, QK 1-term, P RNE-bf16 with l summed from the SAME
// rounded p. Partial O -> RNE bf16 per-quarter buffer; l plain-stored.
// ---------------------------------------------------------------------------
__global__ __launch_bounds__(256, 4)
void attn_kernel(const float* __restrict__ xq,
                 const ushort_t* __restrict__ wq_h, const ushort_t* __restrict__ wq_l,
                 const float* __restrict__ bq,
                 const ushort_t* __restrict__ k_hi, const ushort_t* __restrict__ vt_hi,
                 const int* __restrict__ mask,
                 ushort_t* __restrict__ Opart, float* __restrict__ lws) {
  // smem region (18432 B) is QT[128][72] in preamble/epilogue, Kh|Vh in loop.
  __shared__ __align__(16) ushort_t smem[128 * 72];
  __shared__ __align__(16) ushort_t Pbm[4 * 32 * 40];   // per-wave P (32q x 32k)
  __shared__ float Mz[64];
  ushort_t (*QT)[72] = (ushort_t(*)[72])smem;
  ushort_t (*Kh)[72] = (ushort_t(*)[72])smem;              // [key][d]
  ushort_t (*Vh)[72] = (ushort_t(*)[72])(smem + 64 * 72);  // [d][key]
  ushort_t (*Pb)[32][40] = (ushort_t(*)[32][40])Pbm;

  const int tid  = threadIdx.x;
  const int w    = tid >> 6;          // wave 0..3
  const int lane = tid & 63;
  const int ln   = lane & 15;
  const int quad = lane >> 4;

  // XCD swizzle decode: id = r + 8*(x + 16*gtop); group = r + 8*gtop
  const int id    = blockIdx.x;
  const int rxcd  = id & 7;
  const int m     = id >> 3;          // 0..127
  const int xq_i  = m & 15;           // q-block index 0..15
  const int gtop  = m >> 4;           // 0..7
  const int group = rxcd + 8 * gtop;  // 0..63
  const int h     = group & 7;
  const int zz    = group >> 3;       // 0..7
  const int b     = zz >> 2;
  const int quarter = zz & 3;
  const int q0    = xq_i * 128;
  const size_t hb = ((size_t)b * kH + h) * (size_t)(kS * kD);

  // ---- fused Q projection: 32 rows/wave, RNE bf16, LDS transpose ----
  s16x8 aqh[2][2];   // [group][db]
  #pragma unroll
  for (int g = 0; g < 2; ++g) {
    const int qrow = q0 + w * 32 + g * 16 + ln;
    f32x4 C[4];
    #pragma unroll
    for (int eb = 0; eb < 4; ++eb) C[eb] = (f32x4){0.f, 0.f, 0.f, 0.f};
    #pragma unroll
    for (int kc = 0; kc < 2; ++kc) {
      const float* xp = &xq[((size_t)b * kS + qrow) * kDM + h * kD + kc * 32 + quad * 8];
      const float4 x0 = *(const float4*)xp;
      const float4 x1 = *(const float4*)(xp + 4);
      const float xs[8] = {x0.x, x0.y, x0.z, x0.w, x1.x, x1.y, x1.z, x1.w};
      s16x8 ah, al;
      #pragma unroll
      for (int j = 0; j < 8; ++j) {
        ushort_t hi, lo;
        split_bf16(xs[j], hi, lo);
        ah[j] = (short)hi; al[j] = (short)lo;
      }
      #pragma unroll
      for (int eb = 0; eb < 4; ++eb) {
        const s16x8 bh = *(const s16x8*)&wq_h[(size_t)(eb * 16 + ln) * kD + kc * 32 + quad * 8];
        const s16x8 bl = *(const s16x8*)&wq_l[(size_t)(eb * 16 + ln) * kD + kc * 32 + quad * 8];
        C[eb] = __builtin_amdgcn_mfma_f32_16x16x32_bf16(ah, bh, C[eb], 0, 0, 0);
        C[eb] = __builtin_amdgcn_mfma_f32_16x16x32_bf16(ah, bl, C[eb], 0, 0, 0);
        C[eb] = __builtin_amdgcn_mfma_f32_16x16x32_bf16(al, bh, C[eb], 0, 0, 0);
      }
    }
    #pragma unroll
    for (int eb = 0; eb < 4; ++eb) {
      const float be = bq[eb * 16 + ln];
      #pragma unroll
      for (int r = 0; r < 4; ++r)
        QT[w * 32 + g * 16 + quad * 4 + r][eb * 16 + ln] = rne_bf16(C[eb][r] + be);
    }
    // same-wave readback (wave-private rows; compiler inserts lgkmcnt)
    #pragma unroll
    for (int db = 0; db < 2; ++db)
      aqh[g][db] = *(const s16x8*)&QT[w * 32 + g * 16 + ln][db * 32 + quad * 8];
  }
  __syncthreads();   // QT dead; Kh/Vh live

  f32x4 O[2][4];
  #pragma unroll
  for (int g = 0; g < 2; ++g)
    #pragma unroll
    for (int db = 0; db < 4; ++db) O[g][db] = (f32x4){0.f, 0.f, 0.f, 0.f};
  float rs[2][4] = {};

  // ---- k-loop: this quarter's 8 tiles of 64 keys ----
  const int kt0 = quarter * 8;
  for (int kt = kt0; kt < kt0 + 8; ++kt) {
    __syncthreads();
    {
      const ushort_t* gkh = k_hi + hb + (size_t)kt * 64 * kD;
      const ushort_t* gvh = vt_hi + hb + (size_t)kt * 64;
      #pragma unroll
      for (int cc = 0; cc < 2; ++cc) {
        const int id2 = tid + cc * 256;
        const int r = id2 >> 3, c = id2 & 7;
        *(int4*)&Kh[r][c * 8] = *(const int4*)&gkh[r * kD + c * 8];
        *(int4*)&Vh[r][c * 8] = *(const int4*)&gvh[(size_t)r * kS + c * 8];
      }
      if (tid < 64) Mz[tid] = (mask[(size_t)b * kS + kt * 64 + tid] != 0) ? 1.0f : 0.0f;
    }
    __syncthreads();

    #pragma unroll
    for (int h32 = 0; h32 < 2; ++h32) {
      // S = Q K^T for 32 keys x 32 q-rows (1-term)
      f32x4 C[2][2];
      #pragma unroll
      for (int g = 0; g < 2; ++g) {
        C[g][0] = (f32x4){0.f, 0.f, 0.f, 0.f};
        C[g][1] = (f32x4){0.f, 0.f, 0.f, 0.f};
      }
      #pragma unroll
      for (int db = 0; db < 2; ++db) {
        const s16x8 bh0 = *(const s16x8*)&Kh[h32 * 32 + ln][db * 32 + quad * 8];
        const s16x8 bh1 = *(const s16x8*)&Kh[h32 * 32 + 16 + ln][db * 32 + quad * 8];
        #pragma unroll
        for (int g = 0; g < 2; ++g) {
          C[g][0] = __builtin_amdgcn_mfma_f32_16x16x32_bf16(aqh[g][db], bh0, C[g][0], 0, 0, 0);
          C[g][1] = __builtin_amdgcn_mfma_f32_16x16x32_bf16(aqh[g][db], bh1, C[g][1], 0, 0, 0);
        }
      }
      // p = mask*exp(0.25 s) -> RNE bf16; l sums the SAME rounded p
      #pragma unroll
      for (int g = 0; g < 2; ++g) {
        #pragma unroll
        for (int kb = 0; kb < 2; ++kb) {
          const float mz = Mz[h32 * 32 + kb * 16 + ln];
          #pragma unroll
          for (int r = 0; r < 4; ++r) {
            const float p = mz * __expf(0.25f * C[g][kb][r]);
            union { float f; unsigned u; } pa; pa.f = p;
            const unsigned t = pa.u + 0x7fffu + ((pa.u >> 16) & 1u);
            Pb[w][g * 16 + quad * 4 + r][kb * 16 + ln] = (ushort_t)(t >> 16);
            union { unsigned u; float f; } pr; pr.u = t & 0xffff0000u;
            rs[g][r] += pr.f;
          }
        }
      }
      // O += P V; V-frags shared across both q-groups
      {
        const s16x8 ph0 = *(const s16x8*)&Pb[w][ln][quad * 8];
        const s16x8 ph1 = *(const s16x8*)&Pb[w][16 + ln][quad * 8];
        #pragma unroll
        for (int db = 0; db < 4; ++db) {
          const s16x8 vh = *(const s16x8*)&Vh[db * 16 + ln][h32 * 32 + quad * 8];
          O[0][db] = __builtin_amdgcn_mfma_f32_16x16x32_bf16(ph0, vh, O[0][db], 0, 0, 0);
          O[1][db] = __builtin_amdgcn_mfma_f32_16x16x32_bf16(ph1, vh, O[1][db], 0, 0, 0);
        }
      }
    }
  }

  // ---- l partials: 16-lane group reduce, plain store ----
  #pragma unroll
  for (int mm = 1; mm < 16; mm <<= 1) {
    #pragma unroll
    for (int g = 0; g < 2; ++g)
      #pragma unroll
      for (int r = 0; r < 4; ++r) rs[g][r] += __shfl_xor(rs[g][r], mm);
  }
  if (ln == 0) {
    #pragma unroll
    for (int g = 0; g < 2; ++g) {
      float* lp = lws + (size_t)quarter * kNL + ((size_t)b * kH + h) * kS +
                  q0 + w * 32 + g * 16 + quad * 4;
      #pragma unroll
      for (int r = 0; r < 4; ++r) lp[r] = rs[g][r];
    }
  }

  // ---- O partials: RNE bf16, LDS repack, coalesced stores ----
  __syncthreads();   // Kh/Vh dead
  #pragma unroll
  for (int g = 0; g < 2; ++g)
    #pragma unroll
    for (int db = 0; db < 4; ++db)
      #pragma unroll
      for (int r = 0; r < 4; ++r)
        QT[w * 32 + g * 16 + quad * 4 + r][db * 16 + ln] = rne_bf16(O[g][db][r]);
  __syncthreads();
  ushort_t* op = Opart + (size_t)quarter * kNE;
  #pragma unroll
  for (int cc = 0; cc < 4; ++cc) {
    const int id2 = tid + cc * 256;
    const int r = id2 >> 3, c = id2 & 7;
    *(int4*)&op[((size_t)b * kS + q0 + r) * kDM + h * kD + c * 8] = *(int4*)&QT[r][c * 8];
  }
}

// ---------------------------------------------------------------------------
// Kernel 3: MFMA output projection with fused split-K combine (R10 shape).
// t-tile 32, e-tile 128, k-step 32 -> Opart re-read factor 4.
// grid (B*S/32, DM/128), block 256 (4 waves: tsub = w&1, esub = w>>1).
// ---------------------------------------------------------------------------
__global__ __launch_bounds__(256, 2)
void out_proj_kernel(const ushort_t* __restrict__ Opart, const float* __restrict__ lws,
                     const ushort_t* __restrict__ wh, const ushort_t* __restrict__ wl,
                     const float* __restrict__ bo, float* __restrict__ out) {
  __shared__ __align__(16) ushort_t Ah[32][40];
  __shared__ __align__(16) ushort_t Al[32][40];
  __shared__ __align__(16) ushort_t Bh[128][40];
  __shared__ __align__(16) ushort_t Bl[128][40];
  __shared__ float linv[kH][32];
  const int t0 = blockIdx.x * 32;
  const int e0 = blockIdx.y * 128;
  const int b  = t0 >> 11;
  const int s0 = t0 & (kS - 1);
  const int tid  = threadIdx.x;
  const int w    = tid >> 6;
  const int lane = tid & 63;
  const int ln   = lane & 15;
  const int quad = lane >> 4;
  const int tsub = w & 1;
  const int esub = w >> 1;

  {  // 8 heads x 32 rows: one l-sum per thread
    const int hh = tid >> 5, r = tid & 31;
    const size_t base = ((size_t)b * kH + hh) * kS + s0 + r;
    linv[hh][r] = 1.0f / (lws[base] + lws[kNL + base] +
                          lws[2 * kNL + base] + lws[3 * kNL + base]);
  }

  f32x4 C[4];
  #pragma unroll
  for (int eb = 0; eb < 4; ++eb) C[eb] = (f32x4){0.f, 0.f, 0.f, 0.f};

  for (int k0 = 0; k0 < kDM; k0 += 32) {
    __syncthreads();
    const int hh = k0 >> 6;
    // A: 32 rows x 32 cols; sum 4 bf16 partials -> /l -> split (1 chunk/thread)
    {
      const int r = tid >> 3, c4 = (tid & 7) * 4;
      const size_t off = (size_t)(t0 + r) * kDM + k0 + c4;
      float a0 = 0.f, a1 = 0.f, a2 = 0.f, a3 = 0.f;
      #pragma unroll
      for (int q = 0; q < 4; ++q) {
        const int2 u = *(const int2*)&Opart[(size_t)q * kNE + off];
        a0 += bf_to_f((unsigned)u.x & 0xffffu);
        a1 += bf_to_f((unsigned)u.x >> 16);
        a2 += bf_to_f((unsigned)u.y & 0xffffu);
        a3 += bf_to_f((unsigned)u.y >> 16);
      }
      const float li = linv[hh][r];
      a0 *= li; a1 *= li; a2 *= li; a3 *= li;
      ushort_t h4[4], l4[4];
      split_bf16(a0, h4[0], l4[0]);
      split_bf16(a1, h4[1], l4[1]);
      split_bf16(a2, h4[2], l4[2]);
      split_bf16(a3, h4[3], l4[3]);
      int2 hp, lp;
      hp.x = (int)((unsigned)h4[0] | ((unsigned)h4[1] << 16));
      hp.y = (int)((unsigned)h4[2] | ((unsigned)h4[3] << 16));
      lp.x = (int)((unsigned)l4[0] | ((unsigned)l4[1] << 16));
      lp.y = (int)((unsigned)l4[2] | ((unsigned)l4[3] << 16));
      *(int2*)&Ah[r][c4] = hp;
      *(int2*)&Al[r][c4] = lp;
    }
    // B: 128 rows x 32 cols from pre-split permuted Wo (2 chunks/thread)
    #pragma unroll
    for (int cc = 0; cc < 2; ++cc) {
      const int id = tid + cc * 256;
      const int r = id >> 2, c = (id & 3) * 8;
      *(int4*)&Bh[r][c] = *(const int4*)&wh[(size_t)(e0 + r) * kDM + k0 + c];
      *(int4*)&Bl[r][c] = *(const int4*)&wl[(size_t)(e0 + r) * kDM + k0 + c];
    }
    __syncthreads();
    const s16x8 ah = *(const s16x8*)&Ah[tsub * 16 + ln][quad * 8];
    const s16x8 al = *(const s16x8*)&Al[tsub * 16 + ln][quad * 8];
    #pragma unroll
    for (int eb = 0; eb < 4; ++eb) {
      const s16x8 bh = *(const s16x8*)&Bh[esub * 64 + eb * 16 + ln][quad * 8];
      const s16x8 bl = *(const s16x8*)&Bl[esub * 64 + eb * 16 + ln][quad * 8];
      C[eb] = __builtin_amdgcn_mfma_f32_16x16x32_bf16(ah, bh, C[eb], 0, 0, 0);
      C[eb] = __builtin_amdgcn_mfma_f32_16x16x32_bf16(ah, bl, C[eb], 0, 0, 0);
      C[eb] = __builtin_amdgcn_mfma_f32_16x16x32_bf16(al, bh, C[eb], 0, 0, 0);
    }
  }

  #pragma unroll
  for (int eb = 0; eb < 4; ++eb) {
    const int e = e0 + esub * 64 + eb * 16 + ln;
    const float be = bo[e];
    #pragma unroll
    for (int r = 0; r < 4; ++r) {
      const int t = t0 + tsub * 16 + quad * 4 + r;
      out[(size_t)t * kDM + e] = C[eb][r] + be;
    }
  }
}

// ---------------------------------------------------------------------------
extern "C" void kernel_launch(void* const* d_in, const int* in_sizes, int n_in,
                              void* d_out, int out_size, void* d_ws, size_t ws_size,
                              hipStream_t stream) {
  const float* query = (const float*)d_in[0];
  const float* key   = (const float*)d_in[1];
  const float* value = (const float*)d_in[2];
  const float* Wq = (const float*)d_in[3];
  const float* bq = (const float*)d_in[4];
  const float* Wk = (const float*)d_in[5];
  const float* bk = (const float*)d_in[6];
  const float* Wv = (const float*)d_in[7];
  const float* bv = (const float*)d_in[8];
  const float* Wo = (const float*)d_in[9];
  const float* bo = (const float*)d_in[10];
  const int* mask = (const int*)d_in[11];
  float* out = (float*)d_out;

  ushort_t* k_hi  = (ushort_t*)d_ws;            // 4MB
  ushort_t* vt_hi = k_hi + kNE;                 // 4MB
  ushort_t* wo_h  = vt_hi + kNE;                // 512KB
  ushort_t* wo_l  = wo_h + (size_t)kDM * kDM;   // 512KB
  ushort_t* Opart = wo_l + (size_t)kDM * kDM;   // 16MB (4 quarters, bf16)
  float*    lws   = (float*)(Opart + 4 * kNE);  // 512KB (4 quarters)
  ushort_t* wq_h  = (ushort_t*)(lws + 4 * kNL); // 2 x 8KB
  ushort_t* wq_l  = wq_h + kD * kD;             // total ~25.5 MB

  kv_proj_kernel<<<dim3(kB * kS / 64, kH, 3), 256, 0, stream>>>(
      key, value, Wk, bk, Wv, bv, Wo, Wq, wo_h, wo_l, wq_h, wq_l, k_hi, vt_hi);
  attn_kernel<<<dim3(1024), 256, 0, stream>>>(
      query, wq_h, wq_l, bq, k_hi, vt_hi, mask, Opart, lws);
  out_proj_kernel<<<dim3(kB * kS / 32, kDM / 128), 256, 0, stream>>>(
      Opart, lws, wo_h, wo_l, bo, out);
}